// Round 7
// baseline (36611.533 us; speedup 1.0000x reference)
//
#include <hip/hip_runtime.h>
#include <math.h>

#define NB 16
#define NC 512
#define NH 16
#define NW 64
#define NT 128
#define NV 600
#define NE 80
#define EH 256
#define DH 512
#define NSEQ 256     // NB*NH
#define GEH 1024     // 4*EH
#define GDH 2048     // 4*DH

// ---- workspace layout (float offsets) ----
#define OFF_XPRE_F 0ull          // 64*256*1024   (later aliased by embproj)
#define OFF_XPRE_B 16777216ull   // 64*256*1024   (later aliased by decoder scratch)
#define OFF_XT     33554432ull   // 64*256*512    (encoder barrier ctrs; later wv_enc)
#define OFF_ENC    41943040ull   // 256*64*512
#define OFF_WENC   50331648ull   // 2*256*256*4
#define OFF_WDT    50855936ull   // 848*2048
#define OFF_WHT    52592640ull   // 512*512
#define OFF_WCT    52854784ull   // 1024*256
#define OFF_WOUTT  53116928ull   // 256*600
#define OFF_HA     53270528ull
#define OFF_HB     53401600ull
#define OFF_CENC   53532672ull
#define OFF_CDEC   53663744ull   // 16*512  (cdec ping buffer A)
#define OFF_CTX0   53671936ull   // 16*512
#define OFF_OKT    53680128ull   // 768*16 (rows 0..255=O, 256..767=h)
#define WS_FLOATS  53708800ull   // ~214.8 MB

#define GB_STRIDE 1024           // ints per barrier slot (16 group lines + global line)

__device__ __forceinline__ float sigf(float x) {
  return __builtin_amdgcn_rcpf(1.f + __expf(-x));
}
__device__ __forceinline__ float tanhfast(float x) {
  float e = __expf(2.f * x);
  return 1.f - 2.f * __builtin_amdgcn_rcpf(e + 1.f);
}

// ---- coherent (write-through, L2-bypass) scalar/64-bit accessors ----
__device__ __forceinline__ float ldc(const float* p) {
  return __hip_atomic_load(p, __ATOMIC_RELAXED, __HIP_MEMORY_SCOPE_AGENT);
}
__device__ __forceinline__ void stc(float* p, float v) {
  __hip_atomic_store(p, v, __ATOMIC_RELAXED, __HIP_MEMORY_SCOPE_AGENT);
}
__device__ __forceinline__ float2 ldc2(const float* p) {
  unsigned long long u = __hip_atomic_load((const unsigned long long*)p,
                                           __ATOMIC_RELAXED, __HIP_MEMORY_SCOPE_AGENT);
  union { unsigned long long u; float2 f; } c; c.u = u; return c.f;
}
__device__ __forceinline__ void stc2(float* p, float a, float b) {
  union { float2 f; unsigned long long u; } c; c.f = make_float2(a, b);
  __hip_atomic_store((unsigned long long*)p, c.u,
                     __ATOMIC_RELAXED, __HIP_MEMORY_SCOPE_AGENT);
}

// ---- fence-free two-level grid barrier (256 blocks, 16 groups of 16) ----
// All cross-block data uses coherent ldc/stc, so no L2 writeback/invalidate is
// needed here. __syncthreads() drains each wave's vmcnt (stores acked at the
// coherence point) before the arrival add. Fresh counter slot per sync point.
__device__ __forceinline__ void gridbar(int* __restrict__ ctr, int idx) {
  __syncthreads();
  if (threadIdx.x == 0) {
    int* base = ctr + idx * GB_STRIDE;
    int* gc = base + (blockIdx.x >> 4) * 32;   // group line
    int* gl = base + 512;                      // global line
    int old = __hip_atomic_fetch_add(gc, 1, __ATOMIC_RELAXED, __HIP_MEMORY_SCOPE_AGENT);
    if (old == 15)
      __hip_atomic_fetch_add(gl, 1, __ATOMIC_RELAXED, __HIP_MEMORY_SCOPE_AGENT);
    while (__hip_atomic_load(gl, __ATOMIC_RELAXED, __HIP_MEMORY_SCOPE_AGENT) < 16)
      __builtin_amdgcn_s_sleep(8);
  }
  __syncthreads();
}

// ---------- generic transpose ----------
__global__ void k_transpose(float* __restrict__ dst, const float* __restrict__ src,
                            int R, int Cc) {
  int idx = blockIdx.x * 256 + threadIdx.x;
  if (idx >= R * Cc) return;
  int c = idx / R, r = idx - c * R;
  dst[idx] = src[(size_t)r * Cc + c];
}

__global__ void k_prep_wenc(float* __restrict__ dst, const float* __restrict__ whh, int dir) {
  int idx = blockIdx.x * 256 + threadIdx.x;
  int g = idx & 3, j = (idx >> 2) & 255, k = idx >> 10;
  dst[(size_t)dir * 262144 + idx] = whh[((size_t)(g * 256 + j)) * 256 + k];
}

__global__ void k_buildXt(float* __restrict__ Xt, const float* __restrict__ feat) {
  __shared__ float tile[64][65];
  int n = blockIdx.x, cb = blockIdx.y * 64;
  int b = n >> 4, hh = n & 15;
  int tid = threadIdx.x;
  for (int i = 0; i < 16; ++i) {
    int c = (tid >> 6) + i * 4;
    int w = tid & 63;
    tile[c][w] = feat[(((size_t)b * NC + cb + c) * NH + hh) * NW + w];
  }
  __syncthreads();
  for (int i = 0; i < 16; ++i) {
    int w = (tid >> 6) + i * 4;
    int ci = tid & 63;
    Xt[((size_t)(w * NSEQ + n)) * NC + cb + ci] = tile[ci][w];
  }
}

// ---------- fp32 GEMM ----------
__global__ __launch_bounds__(256) void k_gemm_nt(
    const float* __restrict__ A, const float* __restrict__ Wt,
    const float* __restrict__ bias1, const float* __restrict__ bias2,
    float* __restrict__ Cout, int M, int Nn, int K) {
  __shared__ float As[128 * 32];
  __shared__ float Bs[128 * 32];
  int tid = threadIdx.x;
  int mb = blockIdx.x * 128, nb = blockIdx.y * 128;
  int tx = tid & 15, ty = tid >> 4;
  int row0 = ty * 8, col0 = tx * 8;
  float acc[8][8];
#pragma unroll
  for (int i = 0; i < 8; ++i)
#pragma unroll
    for (int j = 0; j < 8; ++j) acc[i][j] = 0.f;
  int lm = tid >> 1, lk = (tid & 1) * 8;
  int sw = 4 * ((lm >> 3) & 7);
  int p0 = (lk + sw) & 31, p1 = (lk + 4 + sw) & 31;
  const float* Ap = A + (size_t)(mb + lm) * K + lk;
  const float* Bp = Wt + (size_t)(nb + lm) * K + lk;
  for (int k0 = 0; k0 < K; k0 += 16) {
    float4 a0 = *(const float4*)(Ap + k0);
    float4 a1 = *(const float4*)(Ap + k0 + 4);
    float4 b0 = *(const float4*)(Bp + k0);
    float4 b1 = *(const float4*)(Bp + k0 + 4);
    __syncthreads();
    *(float4*)&As[lm * 32 + p0] = a0;
    *(float4*)&As[lm * 32 + p1] = a1;
    *(float4*)&Bs[lm * 32 + p0] = b0;
    *(float4*)&Bs[lm * 32 + p1] = b1;
    __syncthreads();
#pragma unroll
    for (int kq = 0; kq < 4; ++kq) {
      float4 av[8], bv[8];
#pragma unroll
      for (int i = 0; i < 8; ++i) {
        int m = row0 + i;
        av[i] = *(float4*)&As[m * 32 + ((kq * 4 + 4 * ((m >> 3) & 7)) & 31)];
      }
#pragma unroll
      for (int j = 0; j < 8; ++j) {
        int n = col0 + j;
        bv[j] = *(float4*)&Bs[n * 32 + ((kq * 4 + 4 * ((n >> 3) & 7)) & 31)];
      }
#pragma unroll
      for (int i = 0; i < 8; ++i)
#pragma unroll
        for (int j = 0; j < 8; ++j)
          acc[i][j] += av[i].x * bv[j].x + av[i].y * bv[j].y
                     + av[i].z * bv[j].z + av[i].w * bv[j].w;
    }
  }
  float bs[8];
#pragma unroll
  for (int j = 0; j < 8; ++j) {
    float v = bias1 ? bias1[nb + col0 + j] : 0.f;
    if (bias2) v += bias2[nb + col0 + j];
    bs[j] = v;
  }
  for (int i = 0; i < 8; ++i) {
    float* cp = Cout + (size_t)(mb + row0 + i) * Nn + nb + col0;
#pragma unroll
    for (int j = 0; j < 8; ++j) cp[j] = acc[i][j] + bs[j];
  }
}

__global__ void k_enc_init(float* __restrict__ h, float* __restrict__ c,
                           const float* __restrict__ Vh0, const float* __restrict__ Vc0,
                           int* __restrict__ ectr) {
  int idx = blockIdx.x * 256 + threadIdx.x;
  if (idx < 64 * GB_STRIDE) ectr[idx] = 0;
  int dir = idx >> 16, u = idx & 255;
  h[idx] = Vh0[dir * 256 + u];
  c[idx] = Vc0[dir * 256 + u];
}

// ---------- persistent encoder: all 64 steps, fence-free barriers ----------
__global__ __launch_bounds__(256, 1) void k_encoder_p(
    float* __restrict__ hA, float* __restrict__ hB, float* __restrict__ cenc,
    const float* __restrict__ wenc, const float* __restrict__ xpreF,
    const float* __restrict__ xpreB, float* __restrict__ encout,
    int* __restrict__ ectr) {
  __shared__ float hT[256 * 65];
  int bid = blockIdx.x;
  int jc = bid & 31, sc = (bid >> 5) & 3, dir = bid >> 7;
  int tid = threadIdx.x, lane = tid & 63;
  int tyu = __builtin_amdgcn_readfirstlane(tid >> 6);
  int dbase = dir * NSEQ + sc * 64;
  int j0 = jc * 8 + tyu * 2;
  const float* wp = wenc + (size_t)dir * 262144 + (size_t)j0 * 4;
  int n = sc * 64 + lane;
  for (int t = 0; t < 64; ++t) {
    const float* hprev = (t & 1) ? hB : hA;
    float* hnext = (t & 1) ? hA : hB;
    for (int i = 0; i < 16; ++i) {
      int idx = tid + 256 * i;
      int s = idx >> 6, k4 = (idx & 63) * 4;
      float2 v01 = ldc2(&hprev[(size_t)(dbase + s) * EH + k4]);
      float2 v23 = ldc2(&hprev[(size_t)(dbase + s) * EH + k4 + 2]);
      hT[(k4 + 0) * 65 + s] = v01.x;
      hT[(k4 + 1) * 65 + s] = v01.y;
      hT[(k4 + 2) * 65 + s] = v23.x;
      hT[(k4 + 3) * 65 + s] = v23.y;
    }
    __syncthreads();
    float acc0[4] = {0.f, 0.f, 0.f, 0.f}, acc1[4] = {0.f, 0.f, 0.f, 0.f};
#pragma unroll 4
    for (int k = 0; k < 256; ++k) {
      float hv = hT[k * 65 + lane];
      float4 w0 = *(const float4*)(wp + (size_t)k * 1024);
      float4 w1 = *(const float4*)(wp + (size_t)k * 1024 + 4);
      acc0[0] += w0.x * hv; acc0[1] += w0.y * hv; acc0[2] += w0.z * hv; acc0[3] += w0.w * hv;
      acc1[0] += w1.x * hv; acc1[1] += w1.y * hv; acc1[2] += w1.z * hv; acc1[3] += w1.w * hv;
    }
    int w = (dir == 0) ? t : (63 - t);
    const float* xp = (dir ? xpreB : xpreF) + (size_t)w * (NSEQ * GEH) + (size_t)n * GEH;
    float hn2[2];
#pragma unroll
    for (int u = 0; u < 2; ++u) {
      int j = j0 + u;
      float* ac = u ? acc1 : acc0;
      float gi_ = ac[0] + xp[j];
      float gf_ = ac[1] + xp[j + 256];
      float gg_ = ac[2] + xp[j + 512];
      float go_ = ac[3] + xp[j + 768];
      size_t ci = (size_t)(dir * NSEQ + n) * EH + j;
      float cold = cenc[ci];
      float cn = sigf(gf_) * cold + sigf(gi_) * tanhfast(gg_);
      cenc[ci] = cn;
      float hn = sigf(go_) * tanhfast(cn);
      hn2[u] = hn;
      encout[((size_t)n * NW + w) * (2 * EH) + dir * EH + j] = hn;
    }
    stc2(&hnext[(size_t)(dir * NSEQ + n) * EH + j0], hn2[0], hn2[1]);
    if (t < 63) gridbar(ectr, t);
  }
}

__global__ void k_conv(const float* __restrict__ hA, const float* __restrict__ cE,
                       const float* __restrict__ enc, float* __restrict__ cdec,
                       float* __restrict__ okT, float* __restrict__ ctx0) {
  int b = blockIdx.x, tid = threadIdx.x;
  for (int d = tid; d < 512; d += 256) {
    float s = 0.f;
    for (int p = 0; p < 1024; ++p) s += enc[((size_t)b * 1024 + p) * 512 + d];
    ctx0[(size_t)b * 512 + d] = s * (1.f / 1024.f);
    int dir = d >> 8, u = d & 255;
    float sh = 0.f, sc_ = 0.f;
    for (int hh = 0; hh < 16; ++hh) {
      size_t idx = ((size_t)(dir * NSEQ + b * 16 + hh)) * EH + u;
      sh += hA[idx]; sc_ += cE[idx];
    }
    cdec[(size_t)b * 512 + d] = sc_ * (1.f / 16.f);
    okT[(size_t)(256 + d) * 16 + b] = sh * (1.f / 16.f);
  }
}

// ---------- O0 + lin_h(h0) ----------
__global__ void k_O0v2(const float* __restrict__ okT, const float* __restrict__ ctx0,
                       const float* __restrict__ wcT, const float* __restrict__ wcb,
                       const float* __restrict__ whT, const float* __restrict__ whb,
                       float* __restrict__ okT_o, float* __restrict__ linh) {
  int b = blockIdx.x, tid = threadIdx.x;
  float a = wcb[tid];
  for (int k = 0; k < 512; ++k)
    a += okT[(size_t)(256 + k) * 16 + b] * wcT[(size_t)k * 256 + tid];
  const float* cb = ctx0 + (size_t)b * 512;
  for (int k = 0; k < 512; ++k)
    a += cb[k] * wcT[(size_t)(512 + k) * 256 + tid];
  okT_o[(size_t)tid * 16 + b] = tanhfast(a);
  for (int d = tid; d < 512; d += 256) {
    float v = whb[d];
    for (int k = 0; k < 512; ++k)
      v += okT[(size_t)(256 + k) * 16 + b] * whT[(size_t)k * 512 + d];
    linh[(size_t)b * 512 + d] = v;
  }
}

__global__ void k_embproj(const int* __restrict__ formulas, const float* __restrict__ emb,
                          const float* __restrict__ wdT, const float* __restrict__ b1,
                          const float* __restrict__ b2, float* __restrict__ ep) {
  int g = blockIdx.x * 256 + threadIdx.x;
  int tb = blockIdx.y;
  int b = tb & 15, t = tb >> 4;
  int tok = formulas[b * NT + t];
  const float* ev = emb + (size_t)tok * NE;
  float a = b1[g] + b2[g];
  for (int k = 0; k < NE; ++k) a += ev[k] * wdT[(size_t)k * GDH + g];
  ep[(size_t)tb * GDH + g] = a;
}

__global__ void k_zero(int* __restrict__ p, int n) {
  int idx = blockIdx.x * 256 + threadIdx.x;
  for (int i = idx; i < n; i += gridDim.x * 256) p[i] = 0;
}

// ---------- logits helper (exp + per-chunk sums), coherent I/O ----------
__device__ __forceinline__ void logits_block(
    int vc, int lane, int wq, const float* __restrict__ okT,
    const float* __restrict__ woutT, const float* __restrict__ woutb,
    float* __restrict__ ev, float* __restrict__ evp) {
  int v = vc * 64 + lane;
  bool valid = v < NV;
  int vl = valid ? v : (NV - 1);
  float acc[4] = {0.f, 0.f, 0.f, 0.f};
  for (int k = 0; k < 256; ++k) {
    float w = woutT[(size_t)k * NV + vl];
    float2 o01 = ldc2(&okT[(size_t)k * 16 + wq * 4]);
    float2 o23 = ldc2(&okT[(size_t)k * 16 + wq * 4 + 2]);
    acc[0] += w * o01.x; acc[1] += w * o01.y; acc[2] += w * o23.x; acc[3] += w * o23.y;
  }
  float bs = woutb[vl];
#pragma unroll
  for (int i = 0; i < 4; ++i) {
    float e = valid ? __expf(acc[i] + bs) : 0.f;
    if (valid) stc(&ev[(size_t)(wq * 4 + i) * NV + v], e);
    float s = e;
#pragma unroll
    for (int m = 1; m < 64; m <<= 1) s += __shfl_xor(s, m, 64);
    if (lane == 0) stc(&evp[(wq * 4 + i) * 16 + vc], s);
  }
}

__device__ __forceinline__ void norm_block(
    int b, int tid, const float* __restrict__ ev, const float* __restrict__ evp,
    float* __restrict__ outp, int t) {
  float tot = 0.f;
#pragma unroll
  for (int i = 0; i < 10; ++i) tot += ldc(&evp[b * 16 + i]);
  float r = __builtin_amdgcn_rcpf(tot);
  float* orow = outp + ((size_t)b * NT + t) * NV;
  stc(&orow[tid], ldc(&ev[b * NV + tid]) * r);
  stc(&orow[tid + 256], ldc(&ev[b * NV + tid + 256]) * r);
  if (tid < 88) stc(&orow[tid + 512], ldc(&ev[b * NV + tid + 512]) * r);
}

// ---------- persistent decoder: 128 steps, 2 fence-free barriers/step ----------
__global__ __launch_bounds__(256, 1) void k_decoder_p(
    const float* __restrict__ wdT, const float* __restrict__ whT,
    const float* __restrict__ wcT, const float* __restrict__ woutT,
    const float* __restrict__ whb, const float* __restrict__ beta,
    const float* __restrict__ wcb, const float* __restrict__ woutb,
    const float* __restrict__ wvenc, const float* __restrict__ enc,
    const float* __restrict__ ep,
    float* __restrict__ okT, float* __restrict__ cdecA, float* __restrict__ cdecB,
    float* __restrict__ gpart, float* __restrict__ ctxp, float* __restrict__ spart,
    float* __restrict__ ev, float* __restrict__ evp, float* __restrict__ linh,
    float* __restrict__ outp, float* __restrict__ tgt, int* __restrict__ ctr) {
  __shared__ float smem[2048];
  int bid = blockIdx.x, tid = threadIdx.x;
  int lane = tid & 63, wq = tid >> 6;
  int bar = 0;

  for (int t = 0; t < NT; ++t) {
    // ======== phase A: gate partials / lazy logits(t-1), then attention ========
    if (bid < 48) {
      // gates: oc = bid/6 (8 o-chunks of 256), kc = bid%6 (6 k-chunks of 128)
      int oc = bid / 6, kc = bid - oc * 6;
      int o = oc * 256 + tid, k0 = kc * 128;
      const float* wp = wdT + (size_t)(80 + k0) * GDH + o;
      const float* sp = okT + (size_t)k0 * 16;
      float acc[16];
#pragma unroll
      for (int i = 0; i < 16; ++i) acc[i] = 0.f;
      for (int kk = 0; kk < 128; ++kk) {
        float w = wp[(size_t)kk * GDH];
#pragma unroll
        for (int h = 0; h < 8; ++h) {
          float2 s2 = ldc2(sp + kk * 16 + h * 2);
          acc[h * 2] += s2.x * w;
          acc[h * 2 + 1] += s2.y * w;
        }
      }
#pragma unroll
      for (int bb = 0; bb < 16; ++bb)
        stc(&gpart[((size_t)(kc * 16 + bb)) * GDH + o], acc[bb]);
    } else if (bid >= 96 && bid < 106) {
      if (t > 0) logits_block(bid - 96, lane, wq, okT, woutT, woutb, ev, evp);
    }
    {
      int b = bid >> 4, pc = bid & 15;
      int d0 = lane * 8;
      float lh[8], bt[8];
      const float* lp = linh + (size_t)b * 512 + d0;
#pragma unroll
      for (int h = 0; h < 4; ++h) {
        float2 l2 = ldc2(lp + h * 2);
        lh[h * 2] = l2.x; lh[h * 2 + 1] = l2.y;
      }
#pragma unroll
      for (int jj = 0; jj < 8; ++jj) bt[jj] = beta[d0 + jj];
      for (int pi = 0; pi < 16; ++pi) {
        int p = pc * 64 + wq * 16 + pi;
        const float* wvp = wvenc + ((size_t)(b * 1024 + p)) * 512 + d0;
        float e = 0.f;
#pragma unroll
        for (int jj = 0; jj < 8; ++jj) e += bt[jj] * tanhfast(lh[jj] + wvp[jj]);
#pragma unroll
        for (int m = 1; m < 64; m <<= 1) e += __shfl_xor(e, m, 64);
        if (lane == 0) smem[wq * 16 + pi] = __expf(e);   // |e|<=5.2, safe
      }
      __syncthreads();
      float a0 = 0.f, a1 = 0.f;
      for (int p = 0; p < 64; ++p) {
        float s = smem[p];
        const float* er = enc + ((size_t)(b * 1024 + pc * 64 + p)) * 512;
        a0 += s * er[tid];
        a1 += s * er[tid + 256];
      }
      stc(&ctxp[((size_t)(b * 16 + pc)) * 512 + tid], a0);
      stc(&ctxp[((size_t)(b * 16 + pc)) * 512 + tid + 256], a1);
      if (tid == 0) {
        float s = 0.f;
#pragma unroll
        for (int p = 0; p < 64; ++p) s += smem[p];
        stc(&spart[b * 16 + pc], s);
      }
    }
    gridbar(ctr, bar++);

    // ======== phase BC: reduce+cell (redundant x4) + O_t/lin_h slices ========
    if (bid < 64) {
      int b = bid >> 2, q = bid & 3;
      const float* cold = (t & 1) ? cdecB : cdecA;
      float* cnew = (t & 1) ? cdecA : cdecB;
      float Ssum = 0.f;
#pragma unroll
      for (int pc = 0; pc < 16; ++pc) Ssum += ldc(&spart[b * 16 + pc]);
      float rS = __builtin_amdgcn_rcpf(Ssum);
      // context -> smem[512..1023]
#pragma unroll
      for (int half = 0; half < 2; ++half) {
        int d = half * 256 + tid;
        float s = 0.f;
#pragma unroll
        for (int pc = 0; pc < 16; ++pc) s += ldc(&ctxp[((size_t)(b * 16 + pc)) * 512 + d]);
        smem[512 + d] = s * rS;
      }
      // cell -> h in smem[0..511]; duplicate writes of identical values are benign
#pragma unroll
      for (int half = 0; half < 2; ++half) {
        int j = half * 256 + tid;
        float g4[4];
#pragma unroll
        for (int gi = 0; gi < 4; ++gi) {
          float v = ep[((size_t)(t * 16 + b)) * GDH + gi * 512 + j];
#pragma unroll
          for (int kc = 0; kc < 6; ++kc)
            v += ldc(&gpart[((size_t)(kc * 16 + b)) * GDH + gi * 512 + j]);
          g4[gi] = v;
        }
        size_t ci = (size_t)b * 512 + j;
        float cn = sigf(g4[1]) * cold[ci] + sigf(g4[0]) * tanhfast(g4[2]);
        cnew[ci] = cn;
        float hn = sigf(g4[3]) * tanhfast(cn);
        smem[j] = hn;
        stc(&okT[(size_t)(256 + j) * 16 + b], hn);
      }
      __syncthreads();
      // O_t slice: outputs q*64 .. q*64+63, k over [h;ctx]=smem[0..1023]
      {
        int ol = tid & 63, kq = tid >> 6;
        int o = q * 64 + ol;
        float a = 0.f;
        const float* wp = wcT + (size_t)(kq * 256) * 256 + o;
        const float* sp = smem + kq * 256;
        for (int k = 0; k < 256; ++k) a += wp[(size_t)k * 256] * sp[k];
        smem[1024 + kq * 64 + ol] = a;
      }
      __syncthreads();
      if (tid < 64) {
        float s = smem[1024 + tid] + smem[1088 + tid] + smem[1152 + tid] + smem[1216 + tid];
        int o = q * 64 + tid;
        stc(&okT[(size_t)o * 16 + b], tanhfast(s + wcb[o]));
      }
      __syncthreads();
      // lin_h slice: outputs q*128 .. q*128+127, k over h=smem[0..511]
      {
        int o2 = tid & 127, kh = tid >> 7;
        int o = q * 128 + o2;
        float a = 0.f;
        const float* wp = whT + (size_t)(kh * 256) * 512 + o;
        const float* sp = smem + kh * 256;
        for (int k = 0; k < 256; ++k) a += wp[(size_t)k * 512] * sp[k];
        smem[1024 + kh * 128 + o2] = a;
      }
      __syncthreads();
      if (tid < 128) {
        int o = q * 128 + tid;
        float s = smem[1024 + tid] + smem[1152 + tid];
        stc(&linh[(size_t)b * 512 + o], s + whb[o]);
      }
    } else if (bid >= 64 && bid < 80) {
      if (t > 0) norm_block(bid - 64, tid, ev, evp, outp, t - 1);
    }
    gridbar(ctr, bar++);
  }

  // ---- tail: logits t=127, normalize, argmax ----
  if (bid >= 96 && bid < 106)
    logits_block(bid - 96, lane, wq, okT, woutT, woutb, ev, evp);
  gridbar(ctr, bar++);
  if (bid < 16) norm_block(bid, tid, ev, evp, outp, NT - 1);
  gridbar(ctr, bar++);
#pragma unroll
  for (int rr = 0; rr < 2; ++rr) {
    int bt = bid * 8 + wq * 2 + rr;
    const float* row = outp + (size_t)bt * NV;
    float bv = -1.f; int bi = 0;
    for (int v = lane; v < NV; v += 64) {
      float x = ldc(&row[v]);
      if (x > bv) { bv = x; bi = v; }
    }
#pragma unroll
    for (int m = 1; m < 64; m <<= 1) {
      float ov = __shfl_xor(bv, m, 64);
      int oi = __shfl_xor(bi, m, 64);
      if (ov > bv || (ov == bv && oi < bi)) { bv = ov; bi = oi; }
    }
    if (lane == 0) tgt[bt] = (float)bi;
  }
}

extern "C" void kernel_launch(void* const* d_in, const int* in_sizes, int n_in,
                              void* d_out, int out_size, void* d_ws, size_t ws_size,
                              hipStream_t stream) {
  (void)in_sizes; (void)n_in; (void)out_size;
  if (ws_size < WS_FLOATS * sizeof(float)) return;

  const float* feat     = (const float*)d_in[0];
  const int*   formulas = (const int*)d_in[1];
  const float* Wih_f    = (const float*)d_in[2];
  const float* Whh_f    = (const float*)d_in[3];
  const float* bih_f    = (const float*)d_in[4];
  const float* bhh_f    = (const float*)d_in[5];
  const float* Wih_b    = (const float*)d_in[6];
  const float* Whh_b    = (const float*)d_in[7];
  const float* bih_b    = (const float*)d_in[8];
  const float* bhh_b    = (const float*)d_in[9];
  const float* emb      = (const float*)d_in[10];
  const float* Wc_w     = (const float*)d_in[11];
  const float* Wc_b     = (const float*)d_in[12];
  const float* Wout_w   = (const float*)d_in[13];
  const float* Wout_b   = (const float*)d_in[14];
  const float* Vh0      = (const float*)d_in[15];
  const float* Vc0      = (const float*)d_in[16];
  const float* beta     = (const float*)d_in[17];
  const float* Wh_w     = (const float*)d_in[18];
  const float* Wh_b     = (const float*)d_in[19];
  const float* Wv_w     = (const float*)d_in[20];
  const float* Wv_b     = (const float*)d_in[21];
  const float* Wdec_ih  = (const float*)d_in[22];
  const float* Wdec_hh  = (const float*)d_in[23];
  const float* bdec_ih  = (const float*)d_in[24];
  const float* bdec_hh  = (const float*)d_in[25];

  float* ws = (float*)d_ws;
  float* xpreF  = ws + OFF_XPRE_F;
  float* xpreB  = ws + OFF_XPRE_B;
  float* xt     = ws + OFF_XT;
  float* encout = ws + OFF_ENC;
  float* wenc   = ws + OFF_WENC;
  float* wdT    = ws + OFF_WDT;
  float* whT    = ws + OFF_WHT;
  float* wcT    = ws + OFF_WCT;
  float* woutT  = ws + OFF_WOUTT;
  float* hA     = ws + OFF_HA;
  float* hB     = ws + OFF_HB;
  float* cenc   = ws + OFF_CENC;
  float* cdecA  = ws + OFF_CDEC;
  float* ctx0   = ws + OFF_CTX0;
  float* okT    = ws + OFF_OKT;
  // decoder scratch aliased into xpreB (free after encoder)
  float* gpart  = xpreB;                 // 6*16*2048 = 196608
  float* ctxp   = gpart + 196608;        // 16*16*512 = 131072
  float* spart  = ctxp + 131072;         // 256
  float* ev     = spart + 256;           // 16*600 = 9600
  float* evp    = ev + 9600;             // 256
  float* linh   = evp + 256;             // 16*512 = 8192
  float* cdecB  = linh + 8192;           // 8192
  int*   dctr   = (int*)(cdecB + 8192);  // 272*1024 ints (decoder barrier slots)
  int*   ectr   = (int*)xt;              // 64*1024 ints (xt dead between GEMMs & wvenc)
  float* embproj = xpreF;                // alias (free after encoder)
  float* wvenc   = xt;                   // alias (written after encoder completes)

  float* out_logits = (float*)d_out;
  float* out_tgt    = out_logits + (size_t)NB * NT * NV;

  // ---- prep ----
  k_transpose<<<(2048 * 336 + 255) / 256, 256, 0, stream>>>(wdT, Wdec_ih, 2048, 336);
  k_transpose<<<(2048 * 512 + 255) / 256, 256, 0, stream>>>(wdT + 336 * 2048, Wdec_hh, 2048, 512);
  k_transpose<<<(512 * 512 + 255) / 256, 256, 0, stream>>>(whT, Wh_w, 512, 512);
  k_transpose<<<(256 * 1024 + 255) / 256, 256, 0, stream>>>(wcT, Wc_w, 256, 1024);
  k_transpose<<<(600 * 256 + 255) / 256, 256, 0, stream>>>(woutT, Wout_w, 600, 256);
  k_prep_wenc<<<1024, 256, 0, stream>>>(wenc, Whh_f, 0);
  k_prep_wenc<<<1024, 256, 0, stream>>>(wenc, Whh_b, 1);
  k_buildXt<<<dim3(256, 8), 256, 0, stream>>>(xt, feat);
  k_gemm_nt<<<dim3(128, 8), 256, 0, stream>>>(xt, Wih_f, bih_f, bhh_f, xpreF, 16384, 1024, 512);
  k_gemm_nt<<<dim3(128, 8), 256, 0, stream>>>(xt, Wih_b, bih_b, bhh_b, xpreB, 16384, 1024, 512);

  // ---- persistent encoder (ectr lives in xt, free after the input GEMMs) ----
  k_enc_init<<<512, 256, 0, stream>>>(hA, cenc, Vh0, Vc0, ectr);
  k_encoder_p<<<256, 256, 0, stream>>>(hA, hB, cenc, wenc, xpreF, xpreB, encout, ectr);

  k_gemm_nt<<<dim3(128, 4), 256, 0, stream>>>(encout, Wv_w, Wv_b, nullptr, wvenc, 16384, 512, 512);
  k_conv<<<16, 256, 0, stream>>>(hA, cenc, encout, cdecA, okT, ctx0);
  k_O0v2<<<16, 256, 0, stream>>>(okT, ctx0, wcT, Wc_b, whT, Wh_b, okT, linh);
  k_embproj<<<dim3(8, 2048), 256, 0, stream>>>(formulas, emb, wdT, bdec_ih, bdec_hh, embproj);
  k_zero<<<64, 256, 0, stream>>>(dctr, 272 * 1024);

  // ---- persistent decoder (2 fence-free barriers/step) ----
  k_decoder_p<<<256, 256, 0, stream>>>(wdT, whT, wcT, woutT, Wh_b, beta, Wc_b, Wout_b,
                                       wvenc, encout, embproj, okT, cdecA, cdecB,
                                       gpart, ctxp, spart, ev, evp, linh,
                                       out_logits, out_tgt, dctr);
}

// Round 8
// 9133.337 us; speedup vs baseline: 4.0086x; 4.0086x over previous
//
#include <hip/hip_runtime.h>
#include <math.h>

#define NB 16
#define NC 512
#define NH 16
#define NW 64
#define NT 128
#define NV 600
#define NE 80
#define EH 256
#define DH 512
#define NSEQ 256     // NB*NH
#define GEH 1024     // 4*EH
#define GDH 2048     // 4*DH

// ---- workspace layout (float offsets) ----
#define OFF_XPRE_F 0ull          // 64*256*1024   (later aliased by embproj)
#define OFF_XPRE_B 16777216ull   // 64*256*1024   (later aliased by decoder scratch)
#define OFF_XT     33554432ull   // 64*256*512    (later aliased by wv_enc)
#define OFF_ENC    41943040ull   // 256*64*512
#define OFF_WENC   50331648ull   // 2*256*256*4
#define OFF_WDT    50855936ull   // 848*2048
#define OFF_WHT    52592640ull   // 512*512
#define OFF_WCT    52854784ull   // 1024*256
#define OFF_WOUTT  53116928ull   // 256*600
#define OFF_HA     53270528ull   // 2*256*256 (final encoder h)
#define OFF_CENC   53532672ull   // 2*256*256 (final encoder c)
#define OFF_CDEC   53663744ull   // 16*512  (cdec ping buffer A)
#define OFF_CTX0   53671936ull   // 16*512
#define OFF_OKT    53680128ull   // 768*16 (rows 0..255=O, 256..767=h)
#define WS_FLOATS  53708800ull   // ~214.8 MB

__device__ __forceinline__ float sigf(float x) {
  return __builtin_amdgcn_rcpf(1.f + __expf(-x));
}
__device__ __forceinline__ float tanhfast(float x) {
  float e = __expf(2.f * x);
  return 1.f - 2.f * __builtin_amdgcn_rcpf(e + 1.f);
}

// ---------- generic transpose ----------
__global__ void k_transpose(float* __restrict__ dst, const float* __restrict__ src,
                            int R, int Cc) {
  int idx = blockIdx.x * 256 + threadIdx.x;
  if (idx >= R * Cc) return;
  int c = idx / R, r = idx - c * R;
  dst[idx] = src[(size_t)r * Cc + c];
}

__global__ void k_prep_wenc(float* __restrict__ dst, const float* __restrict__ whh, int dir) {
  int idx = blockIdx.x * 256 + threadIdx.x;
  int g = idx & 3, j = (idx >> 2) & 255, k = idx >> 10;
  dst[(size_t)dir * 262144 + idx] = whh[((size_t)(g * 256 + j)) * 256 + k];
}

__global__ void k_buildXt(float* __restrict__ Xt, const float* __restrict__ feat) {
  __shared__ float tile[64][65];
  int n = blockIdx.x, cb = blockIdx.y * 64;
  int b = n >> 4, hh = n & 15;
  int tid = threadIdx.x;
  for (int i = 0; i < 16; ++i) {
    int c = (tid >> 6) + i * 4;
    int w = tid & 63;
    tile[c][w] = feat[(((size_t)b * NC + cb + c) * NH + hh) * NW + w];
  }
  __syncthreads();
  for (int i = 0; i < 16; ++i) {
    int w = (tid >> 6) + i * 4;
    int ci = tid & 63;
    Xt[((size_t)(w * NSEQ + n)) * NC + cb + ci] = tile[ci][w];
  }
}

// ---------- fp32 GEMM ----------
__global__ __launch_bounds__(256) void k_gemm_nt(
    const float* __restrict__ A, const float* __restrict__ Wt,
    const float* __restrict__ bias1, const float* __restrict__ bias2,
    float* __restrict__ Cout, int M, int Nn, int K) {
  __shared__ float As[128 * 32];
  __shared__ float Bs[128 * 32];
  int tid = threadIdx.x;
  int mb = blockIdx.x * 128, nb = blockIdx.y * 128;
  int tx = tid & 15, ty = tid >> 4;
  int row0 = ty * 8, col0 = tx * 8;
  float acc[8][8];
#pragma unroll
  for (int i = 0; i < 8; ++i)
#pragma unroll
    for (int j = 0; j < 8; ++j) acc[i][j] = 0.f;
  int lm = tid >> 1, lk = (tid & 1) * 8;
  int sw = 4 * ((lm >> 3) & 7);
  int p0 = (lk + sw) & 31, p1 = (lk + 4 + sw) & 31;
  const float* Ap = A + (size_t)(mb + lm) * K + lk;
  const float* Bp = Wt + (size_t)(nb + lm) * K + lk;
  for (int k0 = 0; k0 < K; k0 += 16) {
    float4 a0 = *(const float4*)(Ap + k0);
    float4 a1 = *(const float4*)(Ap + k0 + 4);
    float4 b0 = *(const float4*)(Bp + k0);
    float4 b1 = *(const float4*)(Bp + k0 + 4);
    __syncthreads();
    *(float4*)&As[lm * 32 + p0] = a0;
    *(float4*)&As[lm * 32 + p1] = a1;
    *(float4*)&Bs[lm * 32 + p0] = b0;
    *(float4*)&Bs[lm * 32 + p1] = b1;
    __syncthreads();
#pragma unroll
    for (int kq = 0; kq < 4; ++kq) {
      float4 av[8], bv[8];
#pragma unroll
      for (int i = 0; i < 8; ++i) {
        int m = row0 + i;
        av[i] = *(float4*)&As[m * 32 + ((kq * 4 + 4 * ((m >> 3) & 7)) & 31)];
      }
#pragma unroll
      for (int j = 0; j < 8; ++j) {
        int n = col0 + j;
        bv[j] = *(float4*)&Bs[n * 32 + ((kq * 4 + 4 * ((n >> 3) & 7)) & 31)];
      }
#pragma unroll
      for (int i = 0; i < 8; ++i)
#pragma unroll
        for (int j = 0; j < 8; ++j)
          acc[i][j] += av[i].x * bv[j].x + av[i].y * bv[j].y
                     + av[i].z * bv[j].z + av[i].w * bv[j].w;
    }
  }
  float bs[8];
#pragma unroll
  for (int j = 0; j < 8; ++j) {
    float v = bias1 ? bias1[nb + col0 + j] : 0.f;
    if (bias2) v += bias2[nb + col0 + j];
    bs[j] = v;
  }
  for (int i = 0; i < 8; ++i) {
    float* cp = Cout + (size_t)(mb + row0 + i) * Nn + nb + col0;
#pragma unroll
    for (int j = 0; j < 8; ++j) cp[j] = acc[i][j] + bs[j];
  }
}

// ---------- seq-partitioned encoder: zero grid sync, one dispatch ----------
// 128 blocks = 2 dir x 64 groups of 4 seqs. Each block owns its sequences'
// h (LDS) and c (regs) across all 64 steps. Weight slice is L2-resident.
__global__ __launch_bounds__(256) void k_encoder_s(
    const float* __restrict__ wenc, const float* __restrict__ xpreF,
    const float* __restrict__ xpreB, const float* __restrict__ Vh0,
    const float* __restrict__ Vc0, float* __restrict__ encout,
    float* __restrict__ hT_out, float* __restrict__ cT_out) {
  __shared__ float hs[4][256];
  int bid = blockIdx.x;
  int dir = bid >> 6;
  int s0 = (bid & 63) * 4;
  int j = threadIdx.x;
  float c[4];
  {
    float h0 = Vh0[dir * 256 + j];
    float c0v = Vc0[dir * 256 + j];
#pragma unroll
    for (int s = 0; s < 4; ++s) { hs[s][j] = h0; c[s] = c0v; }
  }
  __syncthreads();
  const float* wp = wenc + (size_t)dir * 262144 + (size_t)j * 4;
  const float* xbase = dir ? xpreB : xpreF;
  for (int t = 0; t < 64; ++t) {
    int w = dir ? (63 - t) : t;
    float acc[4][4];
#pragma unroll
    for (int s = 0; s < 4; ++s)
#pragma unroll
      for (int g = 0; g < 4; ++g) acc[s][g] = 0.f;
#pragma unroll 4
    for (int k = 0; k < 256; ++k) {
      float4 w4 = *(const float4*)(wp + (size_t)k * 1024);
      float h0k = hs[0][k], h1k = hs[1][k], h2k = hs[2][k], h3k = hs[3][k];
      acc[0][0] += w4.x * h0k; acc[0][1] += w4.y * h0k; acc[0][2] += w4.z * h0k; acc[0][3] += w4.w * h0k;
      acc[1][0] += w4.x * h1k; acc[1][1] += w4.y * h1k; acc[1][2] += w4.z * h1k; acc[1][3] += w4.w * h1k;
      acc[2][0] += w4.x * h2k; acc[2][1] += w4.y * h2k; acc[2][2] += w4.z * h2k; acc[2][3] += w4.w * h2k;
      acc[3][0] += w4.x * h3k; acc[3][1] += w4.y * h3k; acc[3][2] += w4.z * h3k; acc[3][3] += w4.w * h3k;
    }
    __syncthreads();
#pragma unroll
    for (int s = 0; s < 4; ++s) {
      int n = s0 + s;
      const float* xp = xbase + ((size_t)w * NSEQ + n) * GEH;
      float gi_ = acc[s][0] + xp[j];
      float gf_ = acc[s][1] + xp[j + 256];
      float gg_ = acc[s][2] + xp[j + 512];
      float go_ = acc[s][3] + xp[j + 768];
      float cn = sigf(gf_) * c[s] + sigf(gi_) * tanhfast(gg_);
      c[s] = cn;
      float hn = sigf(go_) * tanhfast(cn);
      hs[s][j] = hn;
      encout[((size_t)n * NW + w) * (2 * EH) + dir * EH + j] = hn;
    }
    __syncthreads();
  }
#pragma unroll
  for (int s = 0; s < 4; ++s) {
    int n = s0 + s;
    hT_out[((size_t)(dir * NSEQ + n)) * EH + j] = hs[s][j];
    cT_out[((size_t)(dir * NSEQ + n)) * EH + j] = c[s];
  }
}

__global__ void k_conv(const float* __restrict__ hA, const float* __restrict__ cE,
                       const float* __restrict__ enc, float* __restrict__ cdec,
                       float* __restrict__ okT, float* __restrict__ ctx0) {
  int b = blockIdx.x, tid = threadIdx.x;
  for (int d = tid; d < 512; d += 256) {
    float s = 0.f;
    for (int p = 0; p < 1024; ++p) s += enc[((size_t)b * 1024 + p) * 512 + d];
    ctx0[(size_t)b * 512 + d] = s * (1.f / 1024.f);
    int dir = d >> 8, u = d & 255;
    float sh = 0.f, sc_ = 0.f;
    for (int hh = 0; hh < 16; ++hh) {
      size_t idx = ((size_t)(dir * NSEQ + b * 16 + hh)) * EH + u;
      sh += hA[idx]; sc_ += cE[idx];
    }
    cdec[(size_t)b * 512 + d] = sc_ * (1.f / 16.f);
    okT[(size_t)(256 + d) * 16 + b] = sh * (1.f / 16.f);
  }
}

// ---------- O0 + lin_h(h0) ----------
__global__ void k_O0v2(const float* __restrict__ okT, const float* __restrict__ ctx0,
                       const float* __restrict__ wcT, const float* __restrict__ wcb,
                       const float* __restrict__ whT, const float* __restrict__ whb,
                       float* __restrict__ okT_o, float* __restrict__ linh) {
  int b = blockIdx.x, tid = threadIdx.x;
  float a = wcb[tid];
  for (int k = 0; k < 512; ++k)
    a += okT[(size_t)(256 + k) * 16 + b] * wcT[(size_t)k * 256 + tid];
  const float* cb = ctx0 + (size_t)b * 512;
  for (int k = 0; k < 512; ++k)
    a += cb[k] * wcT[(size_t)(512 + k) * 256 + tid];
  okT_o[(size_t)tid * 16 + b] = tanhfast(a);
  for (int d = tid; d < 512; d += 256) {
    float v = whb[d];
    for (int k = 0; k < 512; ++k)
      v += okT[(size_t)(256 + k) * 16 + b] * whT[(size_t)k * 512 + d];
    linh[(size_t)b * 512 + d] = v;
  }
}

__global__ void k_embproj(const int* __restrict__ formulas, const float* __restrict__ emb,
                          const float* __restrict__ wdT, const float* __restrict__ b1,
                          const float* __restrict__ b2, float* __restrict__ ep) {
  int g = blockIdx.x * 256 + threadIdx.x;
  int tb = blockIdx.y;
  int b = tb & 15, t = tb >> 4;
  int tok = formulas[b * NT + t];
  const float* ev = emb + (size_t)tok * NE;
  float a = b1[g] + b2[g];
  for (int k = 0; k < NE; ++k) a += ev[k] * wdT[(size_t)k * GDH + g];
  ep[(size_t)tb * GDH + g] = a;
}

// ---------- logits helper (exp + per-chunk sums) ----------
__device__ __forceinline__ void logits_block(
    int vc, int lane, int wq, const float* __restrict__ okT,
    const float* __restrict__ woutT, const float* __restrict__ woutb,
    float* __restrict__ ev, float* __restrict__ evp) {
  int v = vc * 64 + lane;
  bool valid = v < NV;
  int vl = valid ? v : (NV - 1);
  float acc[4] = {0.f, 0.f, 0.f, 0.f};
  for (int k = 0; k < 256; ++k) {
    float w = woutT[(size_t)k * NV + vl];
    float4 o4 = *(const float4*)&okT[(size_t)k * 16 + wq * 4];
    acc[0] += w * o4.x; acc[1] += w * o4.y; acc[2] += w * o4.z; acc[3] += w * o4.w;
  }
  float bs = woutb[vl];
#pragma unroll
  for (int i = 0; i < 4; ++i) {
    float e = valid ? __expf(acc[i] + bs) : 0.f;
    if (valid) ev[(size_t)(wq * 4 + i) * NV + v] = e;
    float s = e;
#pragma unroll
    for (int m = 1; m < 64; m <<= 1) s += __shfl_xor(s, m, 64);
    if (lane == 0) evp[(wq * 4 + i) * 16 + vc] = s;
  }
}

__device__ __forceinline__ void norm_block(
    int b, int tid, const float* __restrict__ ev, const float* __restrict__ evp,
    float* __restrict__ outp, int t) {
  float tot = 0.f;
#pragma unroll
  for (int i = 0; i < 10; ++i) tot += evp[b * 16 + i];
  float r = __builtin_amdgcn_rcpf(tot);
  float* orow = outp + ((size_t)b * NT + t) * NV;
  orow[tid] = ev[b * NV + tid] * r;
  orow[tid + 256] = ev[b * NV + tid + 256] * r;
  if (tid < 88) orow[tid + 512] = ev[b * NV + tid + 512] * r;
}

// ---------- decoder K1: gate partials | lazy logits(t-1) | attention ----------
__global__ __launch_bounds__(256) void k_dec1(
    const float* __restrict__ okT, const float* __restrict__ wdT,
    const float* __restrict__ woutT, const float* __restrict__ woutb,
    const float* __restrict__ linh, const float* __restrict__ beta,
    const float* __restrict__ wvenc, const float* __restrict__ enc,
    float* __restrict__ gpart, float* __restrict__ ctxp,
    float* __restrict__ spart, float* __restrict__ ev, float* __restrict__ evp,
    int t) {
  __shared__ float smem[64];
  int bid = blockIdx.x, tid = threadIdx.x;
  int lane = tid & 63, wq = tid >> 6;

  if (bid < 48) {
    // gates: oc = bid/6 (8 o-chunks of 256), kc = bid%6 (6 k-chunks of 128)
    int oc = bid / 6, kc = bid - oc * 6;
    int o = oc * 256 + tid, k0 = kc * 128;
    const float* wp = wdT + (size_t)(80 + k0) * GDH + o;
    const float* sp = okT + (size_t)k0 * 16;
    float acc[16];
#pragma unroll
    for (int i = 0; i < 16; ++i) acc[i] = 0.f;
    for (int kk = 0; kk < 128; ++kk) {
      float w = wp[(size_t)kk * GDH];
#pragma unroll
      for (int bb = 0; bb < 16; ++bb) acc[bb] += sp[kk * 16 + bb] * w;
    }
#pragma unroll
    for (int bb = 0; bb < 16; ++bb)
      gpart[((size_t)(kc * 16 + bb)) * GDH + o] = acc[bb];
  } else if (bid >= 96 && bid < 106) {
    if (t > 0) logits_block(bid - 96, lane, wq, okT, woutT, woutb, ev, evp);
  }

  // attention: every block does one (b, pc) tile
  {
    int b = bid >> 4, pc = bid & 15;
    int d0 = lane * 8;
    float lh[8], bt[8];
    const float* lp = linh + (size_t)b * 512 + d0;
#pragma unroll
    for (int jj = 0; jj < 8; ++jj) { lh[jj] = lp[jj]; bt[jj] = beta[d0 + jj]; }
    for (int pi = 0; pi < 16; ++pi) {
      int p = pc * 64 + wq * 16 + pi;
      const float* wvp = wvenc + ((size_t)(b * 1024 + p)) * 512 + d0;
      float e = 0.f;
#pragma unroll
      for (int jj = 0; jj < 8; ++jj) e += bt[jj] * tanhfast(lh[jj] + wvp[jj]);
#pragma unroll
      for (int m = 1; m < 64; m <<= 1) e += __shfl_xor(e, m, 64);
      if (lane == 0) smem[wq * 16 + pi] = __expf(e);   // |e|<=5.2, safe
    }
    __syncthreads();
    float a0 = 0.f, a1 = 0.f;
    for (int p = 0; p < 64; ++p) {
      float s = smem[p];
      const float* er = enc + ((size_t)(b * 1024 + pc * 64 + p)) * 512;
      a0 += s * er[tid];
      a1 += s * er[tid + 256];
    }
    ctxp[((size_t)(b * 16 + pc)) * 512 + tid] = a0;
    ctxp[((size_t)(b * 16 + pc)) * 512 + tid + 256] = a1;
    if (tid == 0) {
      float s = 0.f;
#pragma unroll
      for (int p = 0; p < 64; ++p) s += smem[p];
      spart[b * 16 + pc] = s;
    }
  }
}

// ---------- decoder K2: reduce+cell+O_t+lin_h (64 blocks) | norm (16) ----------
__global__ __launch_bounds__(256) void k_dec2(
    const float* __restrict__ gpart, const float* __restrict__ ep,
    const float* __restrict__ ctxp, const float* __restrict__ spart,
    const float* __restrict__ wcT, const float* __restrict__ wcb,
    const float* __restrict__ whT, const float* __restrict__ whb,
    const float* __restrict__ ev, const float* __restrict__ evp,
    float* __restrict__ cdecA, float* __restrict__ cdecB,
    float* __restrict__ okT, float* __restrict__ linh,
    float* __restrict__ outp, int t) {
  __shared__ float smem[1280];
  int bid = blockIdx.x, tid = threadIdx.x;
  if (bid < 64) {
    int b = bid >> 2, q = bid & 3;
    const float* cold = (t & 1) ? cdecB : cdecA;
    float* cnew = (t & 1) ? cdecA : cdecB;
    float Ssum = 0.f;
#pragma unroll
    for (int pc = 0; pc < 16; ++pc) Ssum += spart[b * 16 + pc];
    float rS = __builtin_amdgcn_rcpf(Ssum);
#pragma unroll
    for (int half = 0; half < 2; ++half) {
      int d = half * 256 + tid;
      float s = 0.f;
#pragma unroll
      for (int pc = 0; pc < 16; ++pc) s += ctxp[((size_t)(b * 16 + pc)) * 512 + d];
      smem[512 + d] = s * rS;
    }
#pragma unroll
    for (int half = 0; half < 2; ++half) {
      int j = half * 256 + tid;
      float g4[4];
#pragma unroll
      for (int gi = 0; gi < 4; ++gi) {
        float v = ep[((size_t)(t * 16 + b)) * GDH + gi * 512 + j];
#pragma unroll
        for (int kc = 0; kc < 6; ++kc)
          v += gpart[((size_t)(kc * 16 + b)) * GDH + gi * 512 + j];
        g4[gi] = v;
      }
      size_t ci = (size_t)b * 512 + j;
      float cn = sigf(g4[1]) * cold[ci] + sigf(g4[0]) * tanhfast(g4[2]);
      cnew[ci] = cn;
      float hn = sigf(g4[3]) * tanhfast(cn);
      smem[j] = hn;
      okT[(size_t)(256 + j) * 16 + b] = hn;
    }
    __syncthreads();
    // O_t slice: outputs q*64 .. q*64+63, k over [h;ctx]=smem[0..1023]
    {
      int ol = tid & 63, kq = tid >> 6;
      int o = q * 64 + ol;
      float a = 0.f;
      const float* wp = wcT + (size_t)(kq * 256) * 256 + o;
      const float* sp = smem + kq * 256;
      for (int k = 0; k < 256; ++k) a += wp[(size_t)k * 256] * sp[k];
      smem[1024 + kq * 64 + ol] = a;
    }
    __syncthreads();
    if (tid < 64) {
      float s = smem[1024 + tid] + smem[1088 + tid] + smem[1152 + tid] + smem[1216 + tid];
      int o = q * 64 + tid;
      okT[(size_t)o * 16 + b] = tanhfast(s + wcb[o]);
    }
    __syncthreads();
    // lin_h slice: outputs q*128 .. q*128+127, k over h=smem[0..511]
    {
      int o2 = tid & 127, kh = tid >> 7;
      int o = q * 128 + o2;
      float a = 0.f;
      const float* wp = whT + (size_t)(kh * 256) * 512 + o;
      const float* sp = smem + kh * 256;
      for (int k = 0; k < 256; ++k) a += wp[(size_t)k * 512] * sp[k];
      smem[1024 + kh * 128 + o2] = a;
    }
    __syncthreads();
    if (tid < 128) {
      int o = q * 128 + tid;
      float s = smem[1024 + tid] + smem[1152 + tid];
      linh[(size_t)b * 512 + o] = s + whb[o];
    }
  } else {
    if (t > 0) norm_block(bid - 64, tid, ev, evp, outp, t - 1);
  }
}

// ---------- tail: logits for t=127 ----------
__global__ __launch_bounds__(256) void k_log_tail(
    const float* __restrict__ okT, const float* __restrict__ woutT,
    const float* __restrict__ woutb, float* __restrict__ ev, float* __restrict__ evp) {
  int lane = threadIdx.x & 63, wq = threadIdx.x >> 6;
  logits_block(blockIdx.x, lane, wq, okT, woutT, woutb, ev, evp);
}

__global__ void k_norm(const float* __restrict__ ev, const float* __restrict__ evp,
                       float* __restrict__ outp, int t) {
  norm_block(blockIdx.x, threadIdx.x, ev, evp, outp, t);
}

__global__ void k_argmax(const float* __restrict__ outp, float* __restrict__ tgt) {
  int bt = blockIdx.x;
  int lane = threadIdx.x;
  const float* row = outp + (size_t)bt * NV;
  float bv = -1.f;
  int bi = 0;
  for (int v = lane; v < NV; v += 64) {
    float x = row[v];
    if (x > bv) { bv = x; bi = v; }
  }
#pragma unroll
  for (int m = 1; m < 64; m <<= 1) {
    float ov = __shfl_xor(bv, m, 64);
    int oi = __shfl_xor(bi, m, 64);
    if (ov > bv || (ov == bv && oi < bi)) { bv = ov; bi = oi; }
  }
  if (lane == 0) tgt[bt] = (float)bi;
}

extern "C" void kernel_launch(void* const* d_in, const int* in_sizes, int n_in,
                              void* d_out, int out_size, void* d_ws, size_t ws_size,
                              hipStream_t stream) {
  (void)in_sizes; (void)n_in; (void)out_size;
  if (ws_size < WS_FLOATS * sizeof(float)) return;

  const float* feat     = (const float*)d_in[0];
  const int*   formulas = (const int*)d_in[1];
  const float* Wih_f    = (const float*)d_in[2];
  const float* Whh_f    = (const float*)d_in[3];
  const float* bih_f    = (const float*)d_in[4];
  const float* bhh_f    = (const float*)d_in[5];
  const float* Wih_b    = (const float*)d_in[6];
  const float* Whh_b    = (const float*)d_in[7];
  const float* bih_b    = (const float*)d_in[8];
  const float* bhh_b    = (const float*)d_in[9];
  const float* emb      = (const float*)d_in[10];
  const float* Wc_w     = (const float*)d_in[11];
  const float* Wc_b     = (const float*)d_in[12];
  const float* Wout_w   = (const float*)d_in[13];
  const float* Wout_b   = (const float*)d_in[14];
  const float* Vh0      = (const float*)d_in[15];
  const float* Vc0      = (const float*)d_in[16];
  const float* beta     = (const float*)d_in[17];
  const float* Wh_w     = (const float*)d_in[18];
  const float* Wh_b     = (const float*)d_in[19];
  const float* Wv_w     = (const float*)d_in[20];
  const float* Wv_b     = (const float*)d_in[21];
  const float* Wdec_ih  = (const float*)d_in[22];
  const float* Wdec_hh  = (const float*)d_in[23];
  const float* bdec_ih  = (const float*)d_in[24];
  const float* bdec_hh  = (const float*)d_in[25];

  float* ws = (float*)d_ws;
  float* xpreF  = ws + OFF_XPRE_F;
  float* xpreB  = ws + OFF_XPRE_B;
  float* xt     = ws + OFF_XT;
  float* encout = ws + OFF_ENC;
  float* wenc   = ws + OFF_WENC;
  float* wdT    = ws + OFF_WDT;
  float* whT    = ws + OFF_WHT;
  float* wcT    = ws + OFF_WCT;
  float* woutT  = ws + OFF_WOUTT;
  float* hA     = ws + OFF_HA;
  float* cenc   = ws + OFF_CENC;
  float* cdecA  = ws + OFF_CDEC;
  float* ctx0   = ws + OFF_CTX0;
  float* okT    = ws + OFF_OKT;
  // decoder scratch aliased into xpreB (free after encoder)
  float* gpart  = xpreB;                 // 6*16*2048 = 196608
  float* ctxp   = gpart + 196608;        // 16*16*512 = 131072
  float* spart  = ctxp + 131072;         // 256
  float* ev     = spart + 256;           // 16*600 = 9600
  float* evp    = ev + 9600;             // 256
  float* linh   = evp + 256;             // 16*512 = 8192
  float* cdecB  = linh + 8192;           // 8192
  float* embproj = xpreF;                // alias (free after encoder)
  float* wvenc   = xt;                   // alias (free after input GEMMs)

  float* out_logits = (float*)d_out;
  float* out_tgt    = out_logits + (size_t)NB * NT * NV;

  // ---- prep ----
  k_transpose<<<(2048 * 336 + 255) / 256, 256, 0, stream>>>(wdT, Wdec_ih, 2048, 336);
  k_transpose<<<(2048 * 512 + 255) / 256, 256, 0, stream>>>(wdT + 336 * 2048, Wdec_hh, 2048, 512);
  k_transpose<<<(512 * 512 + 255) / 256, 256, 0, stream>>>(whT, Wh_w, 512, 512);
  k_transpose<<<(256 * 1024 + 255) / 256, 256, 0, stream>>>(wcT, Wc_w, 256, 1024);
  k_transpose<<<(600 * 256 + 255) / 256, 256, 0, stream>>>(woutT, Wout_w, 600, 256);
  k_prep_wenc<<<1024, 256, 0, stream>>>(wenc, Whh_f, 0);
  k_prep_wenc<<<1024, 256, 0, stream>>>(wenc, Whh_b, 1);
  k_buildXt<<<dim3(256, 8), 256, 0, stream>>>(xt, feat);
  k_gemm_nt<<<dim3(128, 8), 256, 0, stream>>>(xt, Wih_f, bih_f, bhh_f, xpreF, 16384, 1024, 512);
  k_gemm_nt<<<dim3(128, 8), 256, 0, stream>>>(xt, Wih_b, bih_b, bhh_b, xpreB, 16384, 1024, 512);

  // ---- encoder: one dispatch, zero grid sync ----
  k_encoder_s<<<128, 256, 0, stream>>>(wenc, xpreF, xpreB, Vh0, Vc0, encout, hA, cenc);

  k_gemm_nt<<<dim3(128, 4), 256, 0, stream>>>(encout, Wv_w, Wv_b, nullptr, wvenc, 16384, 512, 512);
  k_conv<<<16, 256, 0, stream>>>(hA, cenc, encout, cdecA, okT, ctx0);
  k_O0v2<<<16, 256, 0, stream>>>(okT, ctx0, wcT, Wc_b, whT, Wh_b, okT, linh);
  k_embproj<<<dim3(8, 2048), 256, 0, stream>>>(formulas, emb, wdT, bdec_ih, bdec_hh, embproj);

  // ---- decoder: 2 dispatches per step ----
  for (int t = 0; t < NT; ++t) {
    k_dec1<<<256, 256, 0, stream>>>(okT, wdT, woutT, Wout_b, linh, beta, wvenc, encout,
                                    gpart, ctxp, spart, ev, evp, t);
    k_dec2<<<80, 256, 0, stream>>>(gpart, embproj, ctxp, spart, wcT, Wc_b, whT, Wh_b,
                                   ev, evp, cdecA, cdecB, okT, linh, out_logits, t);
  }
  // ---- tail ----
  k_log_tail<<<10, 256, 0, stream>>>(okT, woutT, Wout_b, ev, evp);
  k_norm<<<16, 256, 0, stream>>>(ev, evp, out_logits, NT - 1);
  k_argmax<<<NB * NT, 64, 0, stream>>>(out_logits, out_tgt);
}

// Round 9
// 8165.285 us; speedup vs baseline: 4.4838x; 1.1186x over previous
//
#include <hip/hip_runtime.h>
#include <math.h>

#define NB 16
#define NC 512
#define NH 16
#define NW 64
#define NT 128
#define NV 600
#define NE 80
#define EH 256
#define DH 512
#define NSEQ 256     // NB*NH
#define GEH 1024     // 4*EH
#define GDH 2048     // 4*DH

// ---- workspace layout (float offsets) ----
#define OFF_XPRE_F 0ull          // 64*256*1024   (later aliased by embproj)
#define OFF_XPRE_B 16777216ull   // 64*256*1024   (later aliased by decoder scratch)
#define OFF_XT     33554432ull   // 64*256*512    (later aliased by wv_enc)
#define OFF_ENC    41943040ull   // 256*64*512
#define OFF_WENC   50331648ull   // 2*256*256*4
#define OFF_WDT    50855936ull   // 848*2048
#define OFF_WHT    52592640ull   // 512*512
#define OFF_WCT    52854784ull   // 1024*256
#define OFF_WOUTT  53116928ull   // 256*600
#define OFF_HA     53270528ull   // 2*256*256 (final encoder h)
#define OFF_CENC   53532672ull   // 2*256*256 (final encoder c)
#define OFF_CDEC   53663744ull   // 16*512  (cdec ping buffer A)
#define OFF_CTX0   53671936ull   // 16*512
#define OFF_OKT    53680128ull   // 768*16 (rows 0..255=O, 256..767=h)
#define WS_FLOATS  53708800ull   // ~214.8 MB

__device__ __forceinline__ float sigf(float x) {
  return __builtin_amdgcn_rcpf(1.f + __expf(-x));
}
__device__ __forceinline__ float tanhfast(float x) {
  float e = __expf(2.f * x);
  return 1.f - 2.f * __builtin_amdgcn_rcpf(e + 1.f);
}

// ---------- generic transpose ----------
__global__ void k_transpose(float* __restrict__ dst, const float* __restrict__ src,
                            int R, int Cc) {
  int idx = blockIdx.x * 256 + threadIdx.x;
  if (idx >= R * Cc) return;
  int c = idx / R, r = idx - c * R;
  dst[idx] = src[(size_t)r * Cc + c];
}

__global__ void k_prep_wenc(float* __restrict__ dst, const float* __restrict__ whh, int dir) {
  int idx = blockIdx.x * 256 + threadIdx.x;
  int g = idx & 3, j = (idx >> 2) & 255, k = idx >> 10;
  dst[(size_t)dir * 262144 + idx] = whh[((size_t)(g * 256 + j)) * 256 + k];
}

__global__ void k_buildXt(float* __restrict__ Xt, const float* __restrict__ feat) {
  __shared__ float tile[64][65];
  int n = blockIdx.x, cb = blockIdx.y * 64;
  int b = n >> 4, hh = n & 15;
  int tid = threadIdx.x;
  for (int i = 0; i < 16; ++i) {
    int c = (tid >> 6) + i * 4;
    int w = tid & 63;
    tile[c][w] = feat[(((size_t)b * NC + cb + c) * NH + hh) * NW + w];
  }
  __syncthreads();
  for (int i = 0; i < 16; ++i) {
    int w = (tid >> 6) + i * 4;
    int ci = tid & 63;
    Xt[((size_t)(w * NSEQ + n)) * NC + cb + ci] = tile[ci][w];
  }
}

// ---------- fp32 GEMM ----------
__global__ __launch_bounds__(256) void k_gemm_nt(
    const float* __restrict__ A, const float* __restrict__ Wt,
    const float* __restrict__ bias1, const float* __restrict__ bias2,
    float* __restrict__ Cout, int M, int Nn, int K) {
  __shared__ float As[128 * 32];
  __shared__ float Bs[128 * 32];
  int tid = threadIdx.x;
  int mb = blockIdx.x * 128, nb = blockIdx.y * 128;
  int tx = tid & 15, ty = tid >> 4;
  int row0 = ty * 8, col0 = tx * 8;
  float acc[8][8];
#pragma unroll
  for (int i = 0; i < 8; ++i)
#pragma unroll
    for (int j = 0; j < 8; ++j) acc[i][j] = 0.f;
  int lm = tid >> 1, lk = (tid & 1) * 8;
  int sw = 4 * ((lm >> 3) & 7);
  int p0 = (lk + sw) & 31, p1 = (lk + 4 + sw) & 31;
  const float* Ap = A + (size_t)(mb + lm) * K + lk;
  const float* Bp = Wt + (size_t)(nb + lm) * K + lk;
  for (int k0 = 0; k0 < K; k0 += 16) {
    float4 a0 = *(const float4*)(Ap + k0);
    float4 a1 = *(const float4*)(Ap + k0 + 4);
    float4 b0 = *(const float4*)(Bp + k0);
    float4 b1 = *(const float4*)(Bp + k0 + 4);
    __syncthreads();
    *(float4*)&As[lm * 32 + p0] = a0;
    *(float4*)&As[lm * 32 + p1] = a1;
    *(float4*)&Bs[lm * 32 + p0] = b0;
    *(float4*)&Bs[lm * 32 + p1] = b1;
    __syncthreads();
#pragma unroll
    for (int kq = 0; kq < 4; ++kq) {
      float4 av[8], bv[8];
#pragma unroll
      for (int i = 0; i < 8; ++i) {
        int m = row0 + i;
        av[i] = *(float4*)&As[m * 32 + ((kq * 4 + 4 * ((m >> 3) & 7)) & 31)];
      }
#pragma unroll
      for (int j = 0; j < 8; ++j) {
        int n = col0 + j;
        bv[j] = *(float4*)&Bs[n * 32 + ((kq * 4 + 4 * ((n >> 3) & 7)) & 31)];
      }
#pragma unroll
      for (int i = 0; i < 8; ++i)
#pragma unroll
        for (int j = 0; j < 8; ++j)
          acc[i][j] += av[i].x * bv[j].x + av[i].y * bv[j].y
                     + av[i].z * bv[j].z + av[i].w * bv[j].w;
    }
  }
  float bs[8];
#pragma unroll
  for (int j = 0; j < 8; ++j) {
    float v = bias1 ? bias1[nb + col0 + j] : 0.f;
    if (bias2) v += bias2[nb + col0 + j];
    bs[j] = v;
  }
  for (int i = 0; i < 8; ++i) {
    float* cp = Cout + (size_t)(mb + row0 + i) * Nn + nb + col0;
#pragma unroll
    for (int j = 0; j < 8; ++j) cp[j] = acc[i][j] + bs[j];
  }
}

// ---------- seq-partitioned encoder: zero grid sync, one dispatch ----------
__global__ __launch_bounds__(256) void k_encoder_s(
    const float* __restrict__ wenc, const float* __restrict__ xpreF,
    const float* __restrict__ xpreB, const float* __restrict__ Vh0,
    const float* __restrict__ Vc0, float* __restrict__ encout,
    float* __restrict__ hT_out, float* __restrict__ cT_out) {
  __shared__ float hs[4][256];
  int bid = blockIdx.x;
  int dir = bid >> 6;
  int s0 = (bid & 63) * 4;
  int j = threadIdx.x;
  float c[4];
  {
    float h0 = Vh0[dir * 256 + j];
    float c0v = Vc0[dir * 256 + j];
#pragma unroll
    for (int s = 0; s < 4; ++s) { hs[s][j] = h0; c[s] = c0v; }
  }
  __syncthreads();
  const float* wp = wenc + (size_t)dir * 262144 + (size_t)j * 4;
  const float* xbase = dir ? xpreB : xpreF;
  for (int t = 0; t < 64; ++t) {
    int w = dir ? (63 - t) : t;
    float acc[4][4];
#pragma unroll
    for (int s = 0; s < 4; ++s)
#pragma unroll
      for (int g = 0; g < 4; ++g) acc[s][g] = 0.f;
#pragma unroll 4
    for (int k = 0; k < 256; ++k) {
      float4 w4 = *(const float4*)(wp + (size_t)k * 1024);
      float h0k = hs[0][k], h1k = hs[1][k], h2k = hs[2][k], h3k = hs[3][k];
      acc[0][0] += w4.x * h0k; acc[0][1] += w4.y * h0k; acc[0][2] += w4.z * h0k; acc[0][3] += w4.w * h0k;
      acc[1][0] += w4.x * h1k; acc[1][1] += w4.y * h1k; acc[1][2] += w4.z * h1k; acc[1][3] += w4.w * h1k;
      acc[2][0] += w4.x * h2k; acc[2][1] += w4.y * h2k; acc[2][2] += w4.z * h2k; acc[2][3] += w4.w * h2k;
      acc[3][0] += w4.x * h3k; acc[3][1] += w4.y * h3k; acc[3][2] += w4.z * h3k; acc[3][3] += w4.w * h3k;
    }
    __syncthreads();
#pragma unroll
    for (int s = 0; s < 4; ++s) {
      int n = s0 + s;
      const float* xp = xbase + ((size_t)w * NSEQ + n) * GEH;
      float gi_ = acc[s][0] + xp[j];
      float gf_ = acc[s][1] + xp[j + 256];
      float gg_ = acc[s][2] + xp[j + 512];
      float go_ = acc[s][3] + xp[j + 768];
      float cn = sigf(gf_) * c[s] + sigf(gi_) * tanhfast(gg_);
      c[s] = cn;
      float hn = sigf(go_) * tanhfast(cn);
      hs[s][j] = hn;
      encout[((size_t)n * NW + w) * (2 * EH) + dir * EH + j] = hn;
    }
    __syncthreads();
  }
#pragma unroll
  for (int s = 0; s < 4; ++s) {
    int n = s0 + s;
    hT_out[((size_t)(dir * NSEQ + n)) * EH + j] = hs[s][j];
    cT_out[((size_t)(dir * NSEQ + n)) * EH + j] = c[s];
  }
}

__global__ void k_conv(const float* __restrict__ hA, const float* __restrict__ cE,
                       const float* __restrict__ enc, float* __restrict__ cdec,
                       float* __restrict__ okT, float* __restrict__ ctx0) {
  int b = blockIdx.x, tid = threadIdx.x;
  for (int d = tid; d < 512; d += 256) {
    float s = 0.f;
    for (int p = 0; p < 1024; ++p) s += enc[((size_t)b * 1024 + p) * 512 + d];
    ctx0[(size_t)b * 512 + d] = s * (1.f / 1024.f);
    int dir = d >> 8, u = d & 255;
    float sh = 0.f, sc_ = 0.f;
    for (int hh = 0; hh < 16; ++hh) {
      size_t idx = ((size_t)(dir * NSEQ + b * 16 + hh)) * EH + u;
      sh += hA[idx]; sc_ += cE[idx];
    }
    cdec[(size_t)b * 512 + d] = sc_ * (1.f / 16.f);
    okT[(size_t)(256 + d) * 16 + b] = sh * (1.f / 16.f);
  }
}

// ---------- O0 + lin_h(h0) ----------
__global__ void k_O0v2(const float* __restrict__ okT, const float* __restrict__ ctx0,
                       const float* __restrict__ wcT, const float* __restrict__ wcb,
                       const float* __restrict__ whT, const float* __restrict__ whb,
                       float* __restrict__ okT_o, float* __restrict__ linh) {
  int b = blockIdx.x, tid = threadIdx.x;
  float a = wcb[tid];
  for (int k = 0; k < 512; ++k)
    a += okT[(size_t)(256 + k) * 16 + b] * wcT[(size_t)k * 256 + tid];
  const float* cb = ctx0 + (size_t)b * 512;
  for (int k = 0; k < 512; ++k)
    a += cb[k] * wcT[(size_t)(512 + k) * 256 + tid];
  okT_o[(size_t)tid * 16 + b] = tanhfast(a);
  for (int d = tid; d < 512; d += 256) {
    float v = whb[d];
    for (int k = 0; k < 512; ++k)
      v += okT[(size_t)(256 + k) * 16 + b] * whT[(size_t)k * 512 + d];
    linh[(size_t)b * 512 + d] = v;
  }
}

__global__ void k_embproj(const int* __restrict__ formulas, const float* __restrict__ emb,
                          const float* __restrict__ wdT, const float* __restrict__ b1,
                          const float* __restrict__ b2, float* __restrict__ ep) {
  int g = blockIdx.x * 256 + threadIdx.x;
  int tb = blockIdx.y;
  int b = tb & 15, t = tb >> 4;
  int tok = formulas[b * NT + t];
  const float* ev = emb + (size_t)tok * NE;
  float a = b1[g] + b2[g];
  for (int k = 0; k < NE; ++k) a += ev[k] * wdT[(size_t)k * GDH + g];
  ep[(size_t)tb * GDH + g] = a;
}

// ---------- logits helper (exp + per-chunk sums) ----------
__device__ __forceinline__ void logits_block(
    int vc, int lane, int wq, const float* __restrict__ okT,
    const float* __restrict__ woutT, const float* __restrict__ woutb,
    float* __restrict__ ev, float* __restrict__ evp) {
  int v = vc * 64 + lane;
  bool valid = v < NV;
  int vl = valid ? v : (NV - 1);
  float acc[4] = {0.f, 0.f, 0.f, 0.f};
  for (int k = 0; k < 256; ++k) {
    float w = woutT[(size_t)k * NV + vl];
    float4 o4 = *(const float4*)&okT[(size_t)k * 16 + wq * 4];
    acc[0] += w * o4.x; acc[1] += w * o4.y; acc[2] += w * o4.z; acc[3] += w * o4.w;
  }
  float bs = woutb[vl];
#pragma unroll
  for (int i = 0; i < 4; ++i) {
    float e = valid ? __expf(acc[i] + bs) : 0.f;
    if (valid) ev[(size_t)(wq * 4 + i) * NV + v] = e;
    float s = e;
#pragma unroll
    for (int m = 1; m < 64; m <<= 1) s += __shfl_xor(s, m, 64);
    if (lane == 0) evp[(wq * 4 + i) * 16 + vc] = s;
  }
}

__device__ __forceinline__ void norm_block(
    int b, int tid, const float* __restrict__ ev, const float* __restrict__ evp,
    float* __restrict__ outp, int t) {
  float tot = 0.f;
#pragma unroll
  for (int i = 0; i < 10; ++i) tot += evp[b * 16 + i];
  float r = __builtin_amdgcn_rcpf(tot);
  float* orow = outp + ((size_t)b * NT + t) * NV;
  orow[tid] = ev[b * NV + tid] * r;
  orow[tid + 256] = ev[b * NV + tid + 256] * r;
  if (tid < 88) orow[tid + 512] = ev[b * NV + tid + 512] * r;
}

// ---------- decoder K1: attention (512) | gates (48) | logits (10) ----------
// grid 570; single duty per block for a short critical path.
__global__ __launch_bounds__(256) void k_dec1(
    const float* __restrict__ okT, const float* __restrict__ wdT,
    const float* __restrict__ woutT, const float* __restrict__ woutb,
    const float* __restrict__ linh, const float* __restrict__ beta,
    const float* __restrict__ wvenc, const float* __restrict__ enc,
    float* __restrict__ gpart, float* __restrict__ ctxp,
    float* __restrict__ spart, float* __restrict__ ev, float* __restrict__ evp,
    int t) {
  __shared__ float smem[32];
  int bid = blockIdx.x, tid = threadIdx.x;
  int lane = tid & 63, wq = tid >> 6;

  if (bid < 512) {
    // attention tile: b = bid>>5, pc2 = bid&31 (32 positions each)
    int b = bid >> 5, pc2 = bid & 31;
    int d0 = lane * 8;
    float lh[8], bt[8];
    const float* lp = linh + (size_t)b * 512 + d0;
#pragma unroll
    for (int jj = 0; jj < 8; ++jj) { lh[jj] = lp[jj]; bt[jj] = beta[d0 + jj]; }
#pragma unroll
    for (int pi = 0; pi < 8; ++pi) {
      int p = pc2 * 32 + wq * 8 + pi;
      const float* wvp = wvenc + ((size_t)(b * 1024 + p)) * 512 + d0;
      float e = 0.f;
#pragma unroll
      for (int jj = 0; jj < 8; ++jj) e += bt[jj] * tanhfast(lh[jj] + wvp[jj]);
#pragma unroll
      for (int m = 1; m < 64; m <<= 1) e += __shfl_xor(e, m, 64);
      if (lane == 0) smem[wq * 8 + pi] = __expf(e);   // |e|<=5.2, safe
    }
    __syncthreads();
    float a0 = 0.f, a1 = 0.f;
    const float* erb = enc + ((size_t)(b * 1024 + pc2 * 32)) * 512 + tid * 2;
#pragma unroll 4
    for (int p = 0; p < 32; ++p) {
      float s = smem[p];
      float2 e2 = *(const float2*)(erb + (size_t)p * 512);
      a0 += s * e2.x;
      a1 += s * e2.y;
    }
    *(float2*)&ctxp[((size_t)(b * 32 + pc2)) * 512 + tid * 2] = make_float2(a0, a1);
    if (tid == 0) {
      float s = 0.f;
#pragma unroll
      for (int p = 0; p < 32; ++p) s += smem[p];
      spart[b * 32 + pc2] = s;
    }
  } else if (bid < 560) {
    // gates: oc = idx/6 (8 o-chunks of 256), kc = idx%6 (6 k-chunks of 128)
    int idx = bid - 512;
    int oc = idx / 6, kc = idx - oc * 6;
    int o = oc * 256 + tid, k0 = kc * 128;
    const float* wp = wdT + (size_t)(80 + k0) * GDH + o;
    const float* sp = okT + (size_t)k0 * 16;
    float acc[16];
#pragma unroll
    for (int i = 0; i < 16; ++i) acc[i] = 0.f;
    for (int kk = 0; kk < 128; ++kk) {
      float w = wp[(size_t)kk * GDH];
#pragma unroll
      for (int bb = 0; bb < 16; ++bb) acc[bb] += sp[kk * 16 + bb] * w;
    }
#pragma unroll
    for (int bb = 0; bb < 16; ++bb)
      gpart[((size_t)(kc * 16 + bb)) * GDH + o] = acc[bb];
  } else {
    if (t > 0) logits_block(bid - 560, lane, wq, okT, woutT, woutb, ev, evp);
  }
}

// ---------- decoder K2: reduce+cell+O_t+lin_h (64 blocks) | norm (16) ----------
__global__ __launch_bounds__(256) void k_dec2(
    const float* __restrict__ gpart, const float* __restrict__ ep,
    const float* __restrict__ ctxp, const float* __restrict__ spart,
    const float* __restrict__ wcT, const float* __restrict__ wcb,
    const float* __restrict__ whT, const float* __restrict__ whb,
    const float* __restrict__ ev, const float* __restrict__ evp,
    float* __restrict__ cdecA, float* __restrict__ cdecB,
    float* __restrict__ okT, float* __restrict__ linh,
    float* __restrict__ outp, int t) {
  __shared__ float smem[1280];
  int bid = blockIdx.x, tid = threadIdx.x;
  if (bid < 64) {
    int b = bid >> 2, q = bid & 3;
    const float* cold = (t & 1) ? cdecB : cdecA;
    float* cnew = (t & 1) ? cdecA : cdecB;
    float Ssum = 0.f;
#pragma unroll
    for (int pc = 0; pc < 32; ++pc) Ssum += spart[b * 32 + pc];
    float rS = __builtin_amdgcn_rcpf(Ssum);
    {
      int d = tid * 2;
      float s0 = 0.f, s1 = 0.f;
#pragma unroll 4
      for (int pc = 0; pc < 32; ++pc) {
        float2 c2 = *(const float2*)&ctxp[((size_t)(b * 32 + pc)) * 512 + d];
        s0 += c2.x; s1 += c2.y;
      }
      smem[512 + d] = s0 * rS;
      smem[512 + d + 1] = s1 * rS;
    }
#pragma unroll
    for (int half = 0; half < 2; ++half) {
      int j = half * 256 + tid;
      float g4[4];
#pragma unroll
      for (int gi = 0; gi < 4; ++gi) {
        float v = ep[((size_t)(t * 16 + b)) * GDH + gi * 512 + j];
#pragma unroll
        for (int kc = 0; kc < 6; ++kc)
          v += gpart[((size_t)(kc * 16 + b)) * GDH + gi * 512 + j];
        g4[gi] = v;
      }
      size_t ci = (size_t)b * 512 + j;
      float cn = sigf(g4[1]) * cold[ci] + sigf(g4[0]) * tanhfast(g4[2]);
      cnew[ci] = cn;
      float hn = sigf(g4[3]) * tanhfast(cn);
      smem[j] = hn;
      okT[(size_t)(256 + j) * 16 + b] = hn;
    }
    __syncthreads();
    // O_t slice: outputs q*64 .. q*64+63, k over [h;ctx]=smem[0..1023]
    {
      int ol = tid & 63, kq = tid >> 6;
      int o = q * 64 + ol;
      float a = 0.f;
      const float* wp = wcT + (size_t)(kq * 256) * 256 + o;
      const float* sp = smem + kq * 256;
      for (int k = 0; k < 256; ++k) a += wp[(size_t)k * 256] * sp[k];
      smem[1024 + kq * 64 + ol] = a;
    }
    __syncthreads();
    if (tid < 64) {
      float s = smem[1024 + tid] + smem[1088 + tid] + smem[1152 + tid] + smem[1216 + tid];
      int o = q * 64 + tid;
      okT[(size_t)o * 16 + b] = tanhfast(s + wcb[o]);
    }
    __syncthreads();
    // lin_h slice: outputs q*128 .. q*128+127, k over h=smem[0..511]
    {
      int o2 = tid & 127, kh = tid >> 7;
      int o = q * 128 + o2;
      float a = 0.f;
      const float* wp = whT + (size_t)(kh * 256) * 512 + o;
      const float* sp = smem + kh * 256;
      for (int k = 0; k < 256; ++k) a += wp[(size_t)k * 512] * sp[k];
      smem[1024 + kh * 128 + o2] = a;
    }
    __syncthreads();
    if (tid < 128) {
      int o = q * 128 + tid;
      float s = smem[1024 + tid] + smem[1152 + tid];
      linh[(size_t)b * 512 + o] = s + whb[o];
    }
  } else {
    if (t > 0) norm_block(bid - 64, tid, ev, evp, outp, t - 1);
  }
}

// ---------- tail: logits for t=127 ----------
__global__ __launch_bounds__(256) void k_log_tail(
    const float* __restrict__ okT, const float* __restrict__ woutT,
    const float* __restrict__ woutb, float* __restrict__ ev, float* __restrict__ evp) {
  int lane = threadIdx.x & 63, wq = threadIdx.x >> 6;
  logits_block(blockIdx.x, lane, wq, okT, woutT, woutb, ev, evp);
}

__global__ void k_norm(const float* __restrict__ ev, const float* __restrict__ evp,
                       float* __restrict__ outp, int t) {
  norm_block(blockIdx.x, threadIdx.x, ev, evp, outp, t);
}

__global__ void k_argmax(const float* __restrict__ outp, float* __restrict__ tgt) {
  int bt = blockIdx.x;
  int lane = threadIdx.x;
  const float* row = outp + (size_t)bt * NV;
  float bv = -1.f;
  int bi = 0;
  for (int v = lane; v < NV; v += 64) {
    float x = row[v];
    if (x > bv) { bv = x; bi = v; }
  }
#pragma unroll
  for (int m = 1; m < 64; m <<= 1) {
    float ov = __shfl_xor(bv, m, 64);
    int oi = __shfl_xor(bi, m, 64);
    if (ov > bv || (ov == bv && oi < bi)) { bv = ov; bi = oi; }
  }
  if (lane == 0) tgt[bt] = (float)bi;
}

extern "C" void kernel_launch(void* const* d_in, const int* in_sizes, int n_in,
                              void* d_out, int out_size, void* d_ws, size_t ws_size,
                              hipStream_t stream) {
  (void)in_sizes; (void)n_in; (void)out_size;
  if (ws_size < WS_FLOATS * sizeof(float)) return;

  const float* feat     = (const float*)d_in[0];
  const int*   formulas = (const int*)d_in[1];
  const float* Wih_f    = (const float*)d_in[2];
  const float* Whh_f    = (const float*)d_in[3];
  const float* bih_f    = (const float*)d_in[4];
  const float* bhh_f    = (const float*)d_in[5];
  const float* Wih_b    = (const float*)d_in[6];
  const float* Whh_b    = (const float*)d_in[7];
  const float* bih_b    = (const float*)d_in[8];
  const float* bhh_b    = (const float*)d_in[9];
  const float* emb      = (const float*)d_in[10];
  const float* Wc_w     = (const float*)d_in[11];
  const float* Wc_b     = (const float*)d_in[12];
  const float* Wout_w   = (const float*)d_in[13];
  const float* Wout_b   = (const float*)d_in[14];
  const float* Vh0      = (const float*)d_in[15];
  const float* Vc0      = (const float*)d_in[16];
  const float* beta     = (const float*)d_in[17];
  const float* Wh_w     = (const float*)d_in[18];
  const float* Wh_b     = (const float*)d_in[19];
  const float* Wv_w     = (const float*)d_in[20];
  const float* Wv_b     = (const float*)d_in[21];
  const float* Wdec_ih  = (const float*)d_in[22];
  const float* Wdec_hh  = (const float*)d_in[23];
  const float* bdec_ih  = (const float*)d_in[24];
  const float* bdec_hh  = (const float*)d_in[25];

  float* ws = (float*)d_ws;
  float* xpreF  = ws + OFF_XPRE_F;
  float* xpreB  = ws + OFF_XPRE_B;
  float* xt     = ws + OFF_XT;
  float* encout = ws + OFF_ENC;
  float* wenc   = ws + OFF_WENC;
  float* wdT    = ws + OFF_WDT;
  float* whT    = ws + OFF_WHT;
  float* wcT    = ws + OFF_WCT;
  float* woutT  = ws + OFF_WOUTT;
  float* hA     = ws + OFF_HA;
  float* cenc   = ws + OFF_CENC;
  float* cdecA  = ws + OFF_CDEC;
  float* ctx0   = ws + OFF_CTX0;
  float* okT    = ws + OFF_OKT;
  // decoder scratch aliased into xpreB (free after encoder)
  float* gpart  = xpreB;                 // 6*16*2048 = 196608
  float* ctxp   = gpart + 196608;        // 16*32*512 = 262144
  float* spart  = ctxp + 262144;         // 512
  float* ev     = spart + 512;           // 16*600 = 9600
  float* evp    = ev + 9600;             // 256
  float* linh   = evp + 256;             // 16*512 = 8192
  float* cdecB  = linh + 8192;           // 8192
  float* embproj = xpreF;                // alias (free after encoder)
  float* wvenc   = xt;                   // alias (free after input GEMMs)

  float* out_logits = (float*)d_out;
  float* out_tgt    = out_logits + (size_t)NB * NT * NV;

  // ---- prep ----
  k_transpose<<<(2048 * 336 + 255) / 256, 256, 0, stream>>>(wdT, Wdec_ih, 2048, 336);
  k_transpose<<<(2048 * 512 + 255) / 256, 256, 0, stream>>>(wdT + 336 * 2048, Wdec_hh, 2048, 512);
  k_transpose<<<(512 * 512 + 255) / 256, 256, 0, stream>>>(whT, Wh_w, 512, 512);
  k_transpose<<<(256 * 1024 + 255) / 256, 256, 0, stream>>>(wcT, Wc_w, 256, 1024);
  k_transpose<<<(600 * 256 + 255) / 256, 256, 0, stream>>>(woutT, Wout_w, 600, 256);
  k_prep_wenc<<<1024, 256, 0, stream>>>(wenc, Whh_f, 0);
  k_prep_wenc<<<1024, 256, 0, stream>>>(wenc, Whh_b, 1);
  k_buildXt<<<dim3(256, 8), 256, 0, stream>>>(xt, feat);
  k_gemm_nt<<<dim3(128, 8), 256, 0, stream>>>(xt, Wih_f, bih_f, bhh_f, xpreF, 16384, 1024, 512);
  k_gemm_nt<<<dim3(128, 8), 256, 0, stream>>>(xt, Wih_b, bih_b, bhh_b, xpreB, 16384, 1024, 512);

  // ---- encoder: one dispatch, zero grid sync ----
  k_encoder_s<<<128, 256, 0, stream>>>(wenc, xpreF, xpreB, Vh0, Vc0, encout, hA, cenc);

  k_gemm_nt<<<dim3(128, 4), 256, 0, stream>>>(encout, Wv_w, Wv_b, nullptr, wvenc, 16384, 512, 512);
  k_conv<<<16, 256, 0, stream>>>(hA, cenc, encout, cdecA, okT, ctx0);
  k_O0v2<<<16, 256, 0, stream>>>(okT, ctx0, wcT, Wc_b, whT, Wh_b, okT, linh);
  k_embproj<<<dim3(8, 2048), 256, 0, stream>>>(formulas, emb, wdT, bdec_ih, bdec_hh, embproj);

  // ---- decoder: 2 dispatches per step ----
  for (int t = 0; t < NT; ++t) {
    k_dec1<<<570, 256, 0, stream>>>(okT, wdT, woutT, Wout_b, linh, beta, wvenc, encout,
                                    gpart, ctxp, spart, ev, evp, t);
    k_dec2<<<80, 256, 0, stream>>>(gpart, embproj, ctxp, spart, wcT, Wc_b, whT, Wh_b,
                                   ev, evp, cdecA, cdecB, okT, linh, out_logits, t);
  }
  // ---- tail ----
  k_log_tail<<<10, 256, 0, stream>>>(okT, woutT, Wout_b, ev, evp);
  k_norm<<<16, 256, 0, stream>>>(ev, evp, out_logits, NT - 1);
  k_argmax<<<NB * NT, 64, 0, stream>>>(out_logits, out_tgt);
}